// Round 6
// baseline (261.543 us; speedup 1.0000x reference)
//
#include <hip/hip_runtime.h>
#include <hip/hip_bf16.h>
#include <math.h>

#define Bn 4
#define Sn 512
#define Dn 512
#define DINn 1024
#define Hn 16
#define Pn 64
#define RNn 128
#define DFFn 1368
#define BSn (Bn*Sn)
#define CH 64
#define NCH (Sn/CH)   // 8
#define PSTR 6144     // fused proj row stride: [z(1024) | u(1024) | B(2048) | C(2048)]
#define FSTR 2736     // fused ffn row stride: [h1(1368) | h3(1368)]

typedef __attribute__((ext_vector_type(8))) short short8;
typedef __attribute__((ext_vector_type(4))) float f32x4;

static __device__ __forceinline__ float bf2f(__hip_bfloat16 v){return __bfloat162float(v);}
static __device__ __forceinline__ __hip_bfloat16 f2bf(float v){return __float2bfloat16(v);}
static __device__ __forceinline__ short f2bfs(float v){ __hip_bfloat16 b=f2bf(v); short s; __builtin_memcpy(&s,&b,2); return s; }
static __device__ __forceinline__ float bfs2f(short s){ __hip_bfloat16 b; __builtin_memcpy(&b,&s,2); return bf2f(b); }

// async global->LDS DMA, 16B per lane, dest = wave-uniform base + lane*16
static __device__ __forceinline__ void gl2lds16(const void* gp, void* lp) {
  __builtin_amdgcn_global_load_lds(
      (const __attribute__((address_space(1))) void*)gp,
      (__attribute__((address_space(3))) void*)lp, 16, 0, 0);
}

// ---------------- prep: 8 weight transposes + rmsnorm1+dt, one dispatch ----------------
struct T8 {
  const float* src[8];
  __hip_bfloat16* dst[8];
  int Rr[8], Cc[8], RrPad[8], CcPad[8], gw[8];
  int start[9];
};

__global__ __launch_bounds__(256) void prep_kernel(
    T8 d, const float* __restrict__ x, const float* __restrict__ w,
    const float* __restrict__ mask, const float* __restrict__ Wdt,
    const float* __restrict__ dtb, const float* __restrict__ Alog,
    __hip_bfloat16* __restrict__ outb, float* __restrict__ dt,
    float* __restrict__ la, int tstart) {
  int bid = blockIdx.x, t = threadIdx.x;
  __shared__ __hip_bfloat16 tile[32][33];
  __shared__ float xs[Dn];
  __shared__ float red[4];
  if (bid < tstart) {
    int i = 0;
#pragma unroll
    for (int k = 1; k < 8; ++k) if (bid >= d.start[k]) i = k;
    int rel = bid - d.start[i];
    int gx = rel % d.gw[i], gy = rel / d.gw[i];
    const float* in = d.src[i];
    __hip_bfloat16* out = d.dst[i];
    int Rr = d.Rr[i], Cc = d.Cc[i], RrPad = d.RrPad[i], CcPad = d.CcPad[i];
    int c0 = gx * 32, r0 = gy * 32;
    int tx = t & 31, ty = t >> 5;
    for (int k = ty; k < 32; k += 8) {
      int r = r0 + k, cc = c0 + tx;
      tile[k][tx] = (r < Rr && cc < Cc) ? f2bf(in[(size_t)r * Cc + cc]) : f2bf(0.f);
    }
    __syncthreads();
    for (int k = ty; k < 32; k += 8) {
      int r2 = c0 + k, cc2 = r0 + tx;
      if (r2 < CcPad && cc2 < RrPad) out[(size_t)r2 * RrPad + cc2] = tile[tx][k];
    }
  } else {
    int row = bid - tstart;
    const float* xr = x + (size_t)row * Dn;
    float v0 = xr[t], v1 = xr[t + 256];
    float ss = v0 * v0 + v1 * v1;
#pragma unroll
    for (int o = 32; o > 0; o >>= 1) ss += __shfl_down(ss, o);
    if ((t & 63) == 0) red[t >> 6] = ss;
    __syncthreads();
    float tot = red[0] + red[1] + red[2] + red[3];
    float sc = rsqrtf(tot * (1.f / Dn) + 1e-6f) * mask[row];
    float o0 = v0 * sc * w[t], o1v = v1 * sc * w[t + 256];
    outb[(size_t)row * Dn + t] = f2bf(o0);
    outb[(size_t)row * Dn + t + 256] = f2bf(o1v);
    xs[t] = o0;
    xs[t + 256] = o1v;
    __syncthreads();
    int h = t >> 4, j = t & 15;
    float s = 0.f;
    for (int k = j * 32; k < j * 32 + 32; ++k) s = fmaf(xs[k], Wdt[k * Hn + h], s);
#pragma unroll
    for (int o = 8; o > 0; o >>= 1) s += __shfl_down(s, o, 16);
    if (j == 0) {
      float v = s + dtb[h];
      float sp = (v > 20.f) ? v : log1pf(expf(v));
      float Ah = expf(Alog[h]);
      dt[(size_t)row * Hn + h] = sp;
      la[(size_t)row * Hn + h] = -Ah * sp;
    }
  }
}

// ---------------- rmsnorm (f32 in, no mask) -> bf16 ----------------
__global__ void rmsnorm2_kernel(const float* __restrict__ x,
                                const float* __restrict__ w,
                                __hip_bfloat16* __restrict__ out) {
  int row = blockIdx.x, t = threadIdx.x;
  const float* xr = x + (size_t)row * Dn;
  float v0 = xr[t], v1 = xr[t + 256];
  float ss = v0 * v0 + v1 * v1;
#pragma unroll
  for (int o = 32; o > 0; o >>= 1) ss += __shfl_down(ss, o);
  __shared__ float red[4];
  if ((t & 63) == 0) red[t >> 6] = ss;
  __syncthreads();
  float tot = red[0] + red[1] + red[2] + red[3];
  float sc = rsqrtf(tot * (1.f / Dn) + 1e-6f);
  out[(size_t)row * Dn + t] = f2bf(v0 * sc * w[t]);
  out[(size_t)row * Dn + t + 256] = f2bf(v1 * sc * w[t + 256]);
}

// ---------------- GEMM 128x128, global_load_lds staging (m97-style), bf16 out ----------------
// Requires M%128==0, N%128==0 (grid), K%32==0. Store-guard col < Nstore, row stride ldc.
__global__ __launch_bounds__(256) void gemm_dma_kernel(
    const __hip_bfloat16* __restrict__ A, const __hip_bfloat16* __restrict__ BT,
    __hip_bfloat16* __restrict__ C, int M, int K, int ldc, int Nstore) {
  __shared__ short As[128 * 32];
  __shared__ short Bs[128 * 32];
  int m0 = blockIdx.x * 128, n0 = blockIdx.y * 128;
  int t = threadIdx.x, lane = t & 63, wv = t >> 6;
  const short* Ag = (const short*)A + (size_t)m0 * K;
  const short* Bg = (const short*)BT + (size_t)n0 * K;
  int rA = t >> 2, kc = (t & 3) * 8;     // chunk t -> (row, k-chunk)
  short* As0 = As + wv * 512;            // wave-uniform LDS bases (1KB per wave-issue)
  short* As1 = As + 2048 + wv * 512;
  short* Bs0 = Bs + wv * 512;
  short* Bs1 = Bs + 2048 + wv * 512;
  f32x4 acc[4][4];
#pragma unroll
  for (int i = 0; i < 4; ++i)
#pragma unroll
    for (int j = 0; j < 4; ++j) acc[i][j] = (f32x4){0.f, 0.f, 0.f, 0.f};
  int wm = (wv & 1) * 64, wn = (wv >> 1) * 64;
  int fr = lane & 15, fq = (lane >> 4) * 8;
  int kTiles = K >> 5;
  for (int kt = 0; kt < kTiles; ++kt) {
    int k0 = kt << 5;
    __syncthreads();
    gl2lds16(Ag + (size_t)rA * K + k0 + kc, As0);
    gl2lds16(Ag + (size_t)(rA + 64) * K + k0 + kc, As1);
    gl2lds16(Bg + (size_t)rA * K + k0 + kc, Bs0);
    gl2lds16(Bg + (size_t)(rA + 64) * K + k0 + kc, Bs1);
    __syncthreads();
    short8 af[4], bf[4];
#pragma unroll
    for (int i = 0; i < 4; ++i) af[i] = *(const short8*)&As[(wm + i * 16 + fr) * 32 + fq];
#pragma unroll
    for (int i = 0; i < 4; ++i) bf[i] = *(const short8*)&Bs[(wn + i * 16 + fr) * 32 + fq];
#pragma unroll
    for (int mi = 0; mi < 4; ++mi)
#pragma unroll
      for (int ni = 0; ni < 4; ++ni)
        acc[mi][ni] = __builtin_amdgcn_mfma_f32_16x16x32_bf16(af[mi], bf[ni], acc[mi][ni], 0, 0, 0);
  }
  int fq4 = (lane >> 4) * 4;
#pragma unroll
  for (int mi = 0; mi < 4; ++mi)
#pragma unroll
    for (int ni = 0; ni < 4; ++ni) {
      int col = n0 + wn + ni * 16 + fr;
      if (col < Nstore) {
        int rowb = m0 + wm + mi * 16 + fq4;
#pragma unroll
        for (int r = 0; r < 4; ++r)
          C[(size_t)(rowb + r) * ldc + col] = f2bf(acc[mi][ni][r]);
      }
    }
}

// ---------------- GEMM 64x64 DMA, fused epilogue; GATE=1: A = silu(h1)*h3 from Hf ----------------
// MODE 1: out = aux + acc*mask[row]; MODE 2: out = (aux + acc)*mask[row]. N==512 exact.
template <int MODE, int GATE>
__global__ __launch_bounds__(256) void gemm64_dma_kernel(
    const __hip_bfloat16* __restrict__ A, const __hip_bfloat16* __restrict__ BT,
    const float* __restrict__ aux, const float* __restrict__ mask,
    float* __restrict__ out, int M, int N, int K, int Kreal) {
  __shared__ short As[64 * 32];
  __shared__ short Bs[64 * 32];
  int m0 = blockIdx.x * 64, n0 = blockIdx.y * 64;
  int t = threadIdx.x, lane = t & 63, wv = t >> 6;
  const short* Ag = (const short*)A;
  const short* Bg = (const short*)BT + (size_t)n0 * K;
  int rA = t >> 2, kc = (t & 3) * 8;
  short* AsW = As + wv * 512;
  short* BsW = Bs + wv * 512;
  f32x4 acc[2][2];
#pragma unroll
  for (int i = 0; i < 2; ++i)
#pragma unroll
    for (int j = 0; j < 2; ++j) acc[i][j] = (f32x4){0.f, 0.f, 0.f, 0.f};
  int wm = (wv & 1) * 32, wn = (wv >> 1) * 32;
  int fr = lane & 15, fq = (lane >> 4) * 8;
  int kTiles = K >> 5;
  for (int kt = 0; kt < kTiles; ++kt) {
    int k0 = kt << 5;
    __syncthreads();
    gl2lds16(Bg + (size_t)rA * K + k0 + kc, BsW);
    if (GATE) {
      // A tile = silu(h1)*h3, computed while B DMA is in flight
      int k = k0 + kc;
      const short* hrow = Ag + (size_t)(m0 + rA) * FSTR;
      short8 h1 = *(const short8*)(hrow + k);
      short8 h3 = *(const short8*)(hrow + DFFn + k);
      short8 g;
#pragma unroll
      for (int j = 0; j < 8; ++j) {
        float v = bfs2f(h1[j]);
        float sil = v / (1.f + __expf(-v));
        g[j] = (k + j < Kreal) ? f2bfs(sil * bfs2f(h3[j])) : (short)0;
      }
      *(short8*)&As[t * 8] = g;     // linear, conflict-free
    } else {
      gl2lds16(Ag + (size_t)(m0 + rA) * K + k0 + kc, AsW);
    }
    __syncthreads();
    short8 af[2], bf[2];
#pragma unroll
    for (int i = 0; i < 2; ++i) af[i] = *(const short8*)&As[(wm + i * 16 + fr) * 32 + fq];
#pragma unroll
    for (int i = 0; i < 2; ++i) bf[i] = *(const short8*)&Bs[(wn + i * 16 + fr) * 32 + fq];
#pragma unroll
    for (int mi = 0; mi < 2; ++mi)
#pragma unroll
      for (int ni = 0; ni < 2; ++ni)
        acc[mi][ni] = __builtin_amdgcn_mfma_f32_16x16x32_bf16(af[mi], bf[ni], acc[mi][ni], 0, 0, 0);
  }
  int fq4 = (lane >> 4) * 4;
#pragma unroll
  for (int mi = 0; mi < 2; ++mi)
#pragma unroll
    for (int ni = 0; ni < 2; ++ni) {
      int col = n0 + wn + ni * 16 + fr;
#pragma unroll
      for (int r = 0; r < 4; ++r) {
        int row = m0 + wm + mi * 16 + fq4 + r;
        float m = mask[row];
        size_t a = (size_t)row * N + col;
        float v = acc[mi][ni][r];
        if (MODE == 1) out[a] = aux[a] + v * m;
        else           out[a] = (aux[a] + v) * m;
      }
    }
}

// ---------------- chunked scan: intra-chunk + chunk-state ----------------
__global__ __launch_bounds__(256) void chunk_intra_kernel(
    const __hip_bfloat16* __restrict__ P, const float* __restrict__ dt,
    const float* __restrict__ la, float* __restrict__ ys,
    float* __restrict__ Sbuf, float* __restrict__ ecL, float* __restrict__ ec) {
  int id = blockIdx.x;
  int h = id & 15, c = (id >> 4) & 7, b = id >> 7;
  int t = threadIdx.x, lane = t & 63, wv = t >> 6;
  __shared__ __align__(16) char smem[55040];
  short* sCB = (short*)smem;             // sC [64][136] (phase<=3a), sBt [128][72] (phase>=3b)
  short* sB  = (short*)(smem + 18432);   // [64][136]
  short* sUD = (short*)(smem + 35840);   // [64 p][72]  (s-minor)
  short* sG  = (short*)(smem + 45056);   // [64 t][72]  (s-minor)
  float* scum = (float*)(smem + 54272);  // [64]
  float* sws  = scum + 64;
  float* sdt  = sws + 64;
  int row0 = b * Sn + c * CH;
  const short* Pb = (const short*)P;
#pragma unroll
  for (int i = 0; i < 4; ++i) {
    int idx = t + i * 256;
    int r = idx >> 4, kk = (idx & 15) * 8;
    *(short8*)&sCB[r * 136 + kk] = *(const short8*)(Pb + (size_t)(row0 + r) * PSTR + 4096 + h * 128 + kk);
    *(short8*)&sB [r * 136 + kk] = *(const short8*)(Pb + (size_t)(row0 + r) * PSTR + 2048 + h * 128 + kk);
  }
  if (t < 64) { sdt[t] = dt[(size_t)(row0 + t) * Hn + h]; scum[t] = la[(size_t)(row0 + t) * Hn + h]; }
  __syncthreads();
  if (wv == 0) {
    float v = scum[lane];
#pragma unroll
    for (int o = 1; o < 64; o <<= 1) { float n = __shfl_up(v, o); if (lane >= o) v += n; }
    scum[lane] = v;
    float c63 = __shfl(v, 63);
    sws[lane] = __expf(c63 - v);
    ec[((size_t)((b * NCH + c) * Hn + h)) * 64 + lane] = __expf(v);
    if (lane == 0) ecL[(b * NCH + c) * Hn + h] = __expf(c63);
  }
#pragma unroll
  for (int i = 0; i < 2; ++i) {
    int idx = t + i * 256;
    int s = idx >> 3, pc = (idx & 7) * 8;
    short8 uv = *(const short8*)(Pb + (size_t)(row0 + s) * PSTR + 1024 + h * 64 + pc);
    float dv = sdt[s];
#pragma unroll
    for (int j = 0; j < 8; ++j) sUD[(pc + j) * 72 + s] = f2bfs(bfs2f(uv[j]) * dv);
  }
  __syncthreads();
  int fr = lane & 15, fq = (lane >> 4) * 8, q4 = (lane >> 4) * 4;
  {
    short8 af[4];
#pragma unroll
    for (int k = 0; k < 4; ++k) af[k] = *(short8*)&sCB[(16 * wv + fr) * 136 + k * 32 + fq];
#pragma unroll
    for (int j = 0; j < 4; ++j) {
      f32x4 acc = (f32x4){0.f, 0.f, 0.f, 0.f};
#pragma unroll
      for (int k = 0; k < 4; ++k) {
        short8 bf = *(short8*)&sB[(16 * j + fr) * 136 + k * 32 + fq];
        acc = __builtin_amdgcn_mfma_f32_16x16x32_bf16(af[k], bf, acc, 0, 0, 0);
      }
      int ss = 16 * j + fr;
      float cs = scum[ss];
#pragma unroll
      for (int r = 0; r < 4; ++r) {
        int tt = 16 * wv + q4 + r;
        float w = (ss <= tt) ? __expf(scum[tt] - cs) : 0.f;
        sG[tt * 72 + ss] = f2bfs(acc[r] * w);
      }
    }
  }
  __syncthreads();
#pragma unroll
  for (int i = 0; i < 32; ++i) {
    int idx = t + i * 256;
    int rn = idx >> 6, s = idx & 63;
    sCB[rn * 72 + s] = f2bfs(bfs2f(sB[s * 136 + rn]) * sws[s]);
  }
  __syncthreads();
  {
    short8 ag[2];
#pragma unroll
    for (int k = 0; k < 2; ++k) ag[k] = *(short8*)&sG[(16 * wv + fr) * 72 + k * 32 + fq];
#pragma unroll
    for (int j = 0; j < 4; ++j) {
      f32x4 acc = (f32x4){0.f, 0.f, 0.f, 0.f};
#pragma unroll
      for (int k = 0; k < 2; ++k) {
        short8 bf = *(short8*)&sUD[(16 * j + fr) * 72 + k * 32 + fq];
        acc = __builtin_amdgcn_mfma_f32_16x16x32_bf16(ag[k], bf, acc, 0, 0, 0);
      }
#pragma unroll
      for (int r = 0; r < 4; ++r)
        ys[(size_t)(row0 + 16 * wv + q4 + r) * DINn + h * 64 + 16 * j + fr] = acc[r];
    }
  }
#pragma unroll
  for (int mt0 = 0; mt0 < 2; ++mt0) {
    int mt = wv * 2 + mt0;
    short8 ab[2];
#pragma unroll
    for (int k = 0; k < 2; ++k) ab[k] = *(short8*)&sCB[(16 * mt + fr) * 72 + k * 32 + fq];
#pragma unroll
    for (int j = 0; j < 4; ++j) {
      f32x4 acc = (f32x4){0.f, 0.f, 0.f, 0.f};
#pragma unroll
      for (int k = 0; k < 2; ++k) {
        short8 bf = *(short8*)&sUD[(16 * j + fr) * 72 + k * 32 + fq];
        acc = __builtin_amdgcn_mfma_f32_16x16x32_bf16(ab[k], bf, acc, 0, 0, 0);
      }
#pragma unroll
      for (int r = 0; r < 4; ++r)
        Sbuf[((size_t)((b * NCH + c) * Hn + h) * RNn + 16 * mt + q4 + r) * 64 + 16 * j + fr] = acc[r];
    }
  }
}

// ---------------- prefix over chunk states ----------------
__global__ void chunk_state_kernel(const float* __restrict__ Sbuf, const float* __restrict__ ecL,
                                   float* __restrict__ Hp) {
  int bh = blockIdx.x >> 5;
  int j = (blockIdx.x & 31) * 256 + threadIdx.x;
  int b = bh >> 4, h = bh & 15;
  float hp = 0.f;
#pragma unroll
  for (int c = 0; c < NCH; ++c) {
    size_t addr = ((size_t)((b * NCH + c) * Hn + h)) * 8192 + j;
    Hp[addr] = hp;
    hp = ecL[(b * NCH + c) * Hn + h] * hp + Sbuf[addr];
  }
}

// ---------------- inter-chunk + gate fused ----------------
__global__ __launch_bounds__(256) void inter_gate_kernel(
    const __hip_bfloat16* __restrict__ P, const float* __restrict__ Hp,
    const float* __restrict__ ec, const float* __restrict__ ys,
    const float* __restrict__ Dsk, __hip_bfloat16* __restrict__ y2b) {
  int id = blockIdx.x;
  int h = id & 15, c = (id >> 4) & 7, b = id >> 7;
  int t = threadIdx.x, lane = t & 63, wv = t >> 6;
  __shared__ __align__(16) short sC[64 * 136];
  __shared__ __align__(16) short sHt[64 * 136];
  __shared__ __align__(16) short sz[64 * 64];
  __shared__ __align__(16) short su[64 * 64];
  __shared__ float sec[64];
  int row0 = b * Sn + c * CH;
  const short* Pb = (const short*)P;
#pragma unroll
  for (int i = 0; i < 2; ++i) {
    int idx = t + i * 256;
    int r = idx >> 3, pc = (idx & 7) * 8;
    *(short8*)&sz[r * 64 + pc] = *(const short8*)(Pb + (size_t)(row0 + r) * PSTR + h * 64 + pc);
    *(short8*)&su[r * 64 + pc] = *(const short8*)(Pb + (size_t)(row0 + r) * PSTR + 1024 + h * 64 + pc);
  }
  if (c > 0) {
    size_t hbase = ((size_t)((b * NCH + c) * Hn + h)) * 8192;
#pragma unroll
    for (int i = 0; i < 4; ++i) {
      int idx = t + i * 256;
      int r = idx >> 4, kk = (idx & 15) * 8;
      *(short8*)&sC[r * 136 + kk] = *(const short8*)(Pb + (size_t)(row0 + r) * PSTR + 4096 + h * 128 + kk);
    }
#pragma unroll
    for (int i = 0; i < 32; ++i) {
      int idx = t + i * 256;
      int rn = idx >> 6, p = idx & 63;
      sHt[p * 136 + rn] = f2bfs(Hp[hbase + idx]);
    }
    if (t < 64) sec[t] = ec[((size_t)((b * NCH + c) * Hn + h)) * 64 + t];
  }
  __syncthreads();
  int fr = lane & 15, fq = (lane >> 4) * 8, q4 = (lane >> 4) * 4;
  f32x4 acc[4];
#pragma unroll
  for (int j = 0; j < 4; ++j) acc[j] = (f32x4){0.f, 0.f, 0.f, 0.f};
  if (c > 0) {
    short8 af[4];
#pragma unroll
    for (int k = 0; k < 4; ++k) af[k] = *(short8*)&sC[(16 * wv + fr) * 136 + k * 32 + fq];
#pragma unroll
    for (int j = 0; j < 4; ++j)
#pragma unroll
      for (int k = 0; k < 4; ++k) {
        short8 bf = *(short8*)&sHt[(16 * j + fr) * 136 + k * 32 + fq];
        acc[j] = __builtin_amdgcn_mfma_f32_16x16x32_bf16(af[k], bf, acc[j], 0, 0, 0);
      }
  }
  float dsk = Dsk[h];
#pragma unroll
  for (int j = 0; j < 4; ++j) {
    int col = 16 * j + fr;
#pragma unroll
    for (int r = 0; r < 4; ++r) {
      int tt = 16 * wv + q4 + r;
      size_t a = (size_t)(row0 + tt) * DINn + h * 64 + col;
      float val = ys[a];
      if (c > 0) val += sec[tt] * acc[j][r];
      float uu = bfs2f(su[tt * 64 + col]);
      float zz = bfs2f(sz[tt * 64 + col]);
      float sil = zz / (1.f + __expf(-zz));
      y2b[a] = f2bf((val + uu * dsk) * sil);
    }
  }
}

extern "C" void kernel_launch(void* const* d_in, const int* in_sizes, int n_in,
                              void* d_out, int out_size, void* d_ws, size_t ws_size,
                              hipStream_t stream) {
  const float* x    = (const float*)d_in[0];
  const float* mask = (const float*)d_in[1];
  const float* n1w  = (const float*)d_in[2];
  const float* n2w  = (const float*)d_in[3];
  const float* Wz   = (const float*)d_in[4];
  const float* Wx   = (const float*)d_in[5];
  const float* Wb   = (const float*)d_in[6];
  const float* Wc   = (const float*)d_in[7];
  const float* Wdt  = (const float*)d_in[8];
  const float* dtb  = (const float*)d_in[9];
  const float* Alog = (const float*)d_in[10];
  const float* Dsk  = (const float*)d_in[11];
  const float* Wout = (const float*)d_in[12];
  const float* w1   = (const float*)d_in[13];
  const float* w2   = (const float*)d_in[14];
  const float* w3   = (const float*)d_in[15];

  char* ws = (char*)d_ws;
  size_t off = 0;
  auto alloc = [&](size_t bytes) {
    char* p = ws + off;
    off += (bytes + 255) & ~(size_t)255;
    return p;
  };
  __hip_bfloat16* xnb = (__hip_bfloat16*)alloc((size_t)BSn * Dn * 2);
  __hip_bfloat16* P = (__hip_bfloat16*)alloc((size_t)BSn * PSTR * 2);
  float* dt  = (float*)alloc((size_t)BSn * Hn * 4);
  float* la  = (float*)alloc((size_t)BSn * Hn * 4);
  float* ys  = (float*)alloc((size_t)BSn * DINn * 4);
  float* ecL = (float*)alloc((size_t)Bn * NCH * Hn * 4);
  float* ec  = (float*)alloc((size_t)Bn * NCH * Hn * 64 * 4);
  __hip_bfloat16* WallT = (__hip_bfloat16*)alloc((size_t)PSTR * Dn * 2);   // [z|u|B|C]^T
  __hip_bfloat16* WoutT = (__hip_bfloat16*)alloc((size_t)Dn * DINn * 2);
  __hip_bfloat16* w13T  = (__hip_bfloat16*)alloc((size_t)2816 * Dn * 2);   // [w1|w3|zeros]^T  N-pad 2816
  __hip_bfloat16* w2T   = (__hip_bfloat16*)alloc((size_t)Dn * 1376 * 2);   // K-pad 1376
  // overlaid arena: scan-phase {Sbuf, Hp} then ffn-phase {y2b, xres, Hf}
  char* arena = alloc(34000000);
  float* Sbuf = (float*)arena;                              // 16.78 MB, dead after chunk_state
  float* Hp   = (float*)(arena + 16777216);                 // 16.78 MB, dead after inter_gate
  __hip_bfloat16* y2b = (__hip_bfloat16*)arena;             // 4 MB (over dead Sbuf)
  float* xres = (float*)(arena + 8388608);                  // 4 MB
  __hip_bfloat16* Hf = (__hip_bfloat16*)(arena + 12582912); // 11.2 MB (over dead Hp region)

  // -------- transpose job table --------
  T8 td;
  td.src[0] = Wz;   td.dst[0] = WallT;                      td.Rr[0] = 512;  td.Cc[0] = 1024; td.RrPad[0] = 512;  td.CcPad[0] = 1024;
  td.src[1] = Wx;   td.dst[1] = WallT + (size_t)1024 * 512; td.Rr[1] = 512;  td.Cc[1] = 1024; td.RrPad[1] = 512;  td.CcPad[1] = 1024;
  td.src[2] = Wb;   td.dst[2] = WallT + (size_t)2048 * 512; td.Rr[2] = 512;  td.Cc[2] = 2048; td.RrPad[2] = 512;  td.CcPad[2] = 2048;
  td.src[3] = Wc;   td.dst[3] = WallT + (size_t)4096 * 512; td.Rr[3] = 512;  td.Cc[3] = 2048; td.RrPad[3] = 512;  td.CcPad[3] = 2048;
  td.src[4] = Wout; td.dst[4] = WoutT;                      td.Rr[4] = 1024; td.Cc[4] = 512;  td.RrPad[4] = 1024; td.CcPad[4] = 512;
  td.src[5] = w1;   td.dst[5] = w13T;                       td.Rr[5] = 512;  td.Cc[5] = 1368; td.RrPad[5] = 512;  td.CcPad[5] = 1368;
  td.src[6] = w3;   td.dst[6] = w13T + (size_t)1368 * 512;  td.Rr[6] = 512;  td.Cc[6] = 1368; td.RrPad[6] = 512;  td.CcPad[6] = 1448; // zero rows -> N=2816
  td.src[7] = w2;   td.dst[7] = w2T;                        td.Rr[7] = 1368; td.Cc[7] = 512;  td.RrPad[7] = 1376; td.CcPad[7] = 512;  // zero K-pad cols
  int tot = 0;
  for (int i = 0; i < 8; ++i) {
    td.gw[i] = (td.CcPad[i] + 31) / 32;
    int gh = (td.RrPad[i] + 31) / 32;
    td.start[i] = tot;
    tot += td.gw[i] * gh;
  }
  td.start[8] = tot;   // 5696

  prep_kernel<<<tot + BSn, 256, 0, stream>>>(td, x, n1w, mask, Wdt, dtb, Alog, xnb, dt, la, tot);
  gemm_dma_kernel<<<dim3(16, 48), 256, 0, stream>>>(xnb, WallT, P, BSn, Dn, PSTR, PSTR);
  chunk_intra_kernel<<<Bn * NCH * Hn, 256, 0, stream>>>(P, dt, la, ys, Sbuf, ecL, ec);
  chunk_state_kernel<<<Bn * Hn * 32, 256, 0, stream>>>(Sbuf, ecL, Hp);
  inter_gate_kernel<<<Bn * NCH * Hn, 256, 0, stream>>>(P, Hp, ec, ys, Dsk, y2b);
  gemm64_dma_kernel<1, 0><<<dim3(32, 8), 256, 0, stream>>>(y2b, WoutT, x, mask, xres, BSn, Dn, DINn, DINn);
  rmsnorm2_kernel<<<BSn, 256, 0, stream>>>(xres, n2w, xnb);
  gemm_dma_kernel<<<dim3(16, 22), 256, 0, stream>>>(xnb, w13T, Hf, BSn, Dn, FSTR, FSTR);
  gemm64_dma_kernel<2, 1><<<dim3(32, 8), 256, 0, stream>>>(Hf, w2T, xres, mask, (float*)d_out, BSn, Dn, 1376, DFFn);
}

// Round 7
// 251.425 us; speedup vs baseline: 1.0402x; 1.0402x over previous
//
#include <hip/hip_runtime.h>
#include <hip/hip_bf16.h>
#include <math.h>
#include <type_traits>

#define Bn 4
#define Sn 512
#define Dn 512
#define DINn 1024
#define Hn 16
#define Pn 64
#define RNn 128
#define DFFn 1368
#define BSn (Bn*Sn)
#define CH 64
#define NCH (Sn/CH)   // 8
#define PSTR 6144     // fused proj row stride: [z(1024) | u(1024) | B(2048) | C(2048)]
#define FSTR 2736     // fused ffn row stride: [h1(1368) | h3(1368)]

typedef __attribute__((ext_vector_type(8))) short short8;
typedef __attribute__((ext_vector_type(4))) float f32x4;

static __device__ __forceinline__ float bf2f(__hip_bfloat16 v){return __bfloat162float(v);}
static __device__ __forceinline__ __hip_bfloat16 f2bf(float v){return __float2bfloat16(v);}
static __device__ __forceinline__ short f2bfs(float v){ __hip_bfloat16 b=f2bf(v); short s; __builtin_memcpy(&s,&b,2); return s; }
static __device__ __forceinline__ float bfs2f(short s){ __hip_bfloat16 b; __builtin_memcpy(&b,&s,2); return bf2f(b); }

// ---------------- fused 8-way transpose+cast: f32 [Rr x Cc] -> bf16 [CcPad x RrPad] ----------------
struct T8 {
  const float* src[8];
  __hip_bfloat16* dst[8];
  int Rr[8], Cc[8], RrPad[8], CcPad[8], gw[8];
  int start[9];
};

__global__ void transpose8_kernel(T8 d) {
  int bid = blockIdx.x;
  int i = 0;
#pragma unroll
  for (int k = 1; k < 8; ++k) if (bid >= d.start[k]) i = k;
  int rel = bid - d.start[i];
  int gx = rel % d.gw[i], gy = rel / d.gw[i];
  const float* __restrict__ in = d.src[i];
  __hip_bfloat16* __restrict__ out = d.dst[i];
  int Rr = d.Rr[i], Cc = d.Cc[i], RrPad = d.RrPad[i], CcPad = d.CcPad[i];
  __shared__ __hip_bfloat16 tile[32][33];
  int c0 = gx * 32, r0 = gy * 32;
  int tx = threadIdx.x, ty = threadIdx.y;
  for (int k = ty; k < 32; k += 8) {
    int r = r0 + k, cc = c0 + tx;
    tile[k][tx] = (r < Rr && cc < Cc) ? f2bf(in[(size_t)r * Cc + cc]) : f2bf(0.f);
  }
  __syncthreads();
  for (int k = ty; k < 32; k += 8) {
    int r = c0 + k, cc = r0 + tx;
    if (r < CcPad && cc < RrPad) out[(size_t)r * RrPad + cc] = tile[tx][k];
  }
}

// ---------------- rmsnorm1 * mask -> bf16, fused dt/la ----------------
__global__ void rmsnorm1_dt_kernel(const float* __restrict__ x,
                                   const float* __restrict__ w,
                                   const float* __restrict__ mask,
                                   const float* __restrict__ Wdt,
                                   const float* __restrict__ dtb,
                                   const float* __restrict__ Alog,
                                   __hip_bfloat16* __restrict__ outb,
                                   float* __restrict__ dt, float* __restrict__ la) {
  __shared__ float xs[Dn];
  __shared__ float red[4];
  int row = blockIdx.x, t = threadIdx.x;
  const float* xr = x + (size_t)row * Dn;
  float v0 = xr[t], v1 = xr[t + 256];
  float ss = v0 * v0 + v1 * v1;
#pragma unroll
  for (int o = 32; o > 0; o >>= 1) ss += __shfl_down(ss, o);
  if ((t & 63) == 0) red[t >> 6] = ss;
  __syncthreads();
  float tot = red[0] + red[1] + red[2] + red[3];
  float sc = rsqrtf(tot * (1.f / Dn) + 1e-6f) * mask[row];
  float o0 = v0 * sc * w[t], o1v = v1 * sc * w[t + 256];
  outb[(size_t)row * Dn + t] = f2bf(o0);
  outb[(size_t)row * Dn + t + 256] = f2bf(o1v);
  xs[t] = o0;
  xs[t + 256] = o1v;
  __syncthreads();
  int h = t >> 4, j = t & 15;
  float s = 0.f;
  for (int k = j * 32; k < j * 32 + 32; ++k) s = fmaf(xs[k], Wdt[k * Hn + h], s);
#pragma unroll
  for (int o = 8; o > 0; o >>= 1) s += __shfl_down(s, o, 16);
  if (j == 0) {
    float v = s + dtb[h];
    float sp = (v > 20.f) ? v : log1pf(expf(v));
    float Ah = expf(Alog[h]);
    dt[(size_t)row * Hn + h] = sp;
    la[(size_t)row * Hn + h] = -Ah * sp;
  }
}

// ---------------- rmsnorm (f32 in, no mask) -> bf16 ----------------
__global__ void rmsnorm2_kernel(const float* __restrict__ x,
                                const float* __restrict__ w,
                                __hip_bfloat16* __restrict__ out) {
  int row = blockIdx.x, t = threadIdx.x;
  const float* xr = x + (size_t)row * Dn;
  float v0 = xr[t], v1 = xr[t + 256];
  float ss = v0 * v0 + v1 * v1;
#pragma unroll
  for (int o = 32; o > 0; o >>= 1) ss += __shfl_down(ss, o);
  __shared__ float red[4];
  if ((t & 63) == 0) red[t >> 6] = ss;
  __syncthreads();
  float tot = red[0] + red[1] + red[2] + red[3];
  float sc = rsqrtf(tot * (1.f / Dn) + 1e-6f);
  out[(size_t)row * Dn + t] = f2bf(v0 * sc * w[t]);
  out[(size_t)row * Dn + t + 256] = f2bf(v1 * sc * w[t + 256]);
}

// ---------------- GEMM 128x128: C[M,N] = A[M,K] @ BT[N,K]^T, register-pipelined ----------------
__global__ __launch_bounds__(256) void gemm_kernel(
    const __hip_bfloat16* __restrict__ A, const __hip_bfloat16* __restrict__ BT,
    __hip_bfloat16* __restrict__ C, int M, int N, int K) {
  __shared__ short As[128][40];
  __shared__ short Bs[128][40];
  int m0 = blockIdx.x * 128, n0 = blockIdx.y * 128;
  int t = threadIdx.x;
  int lane = t & 63, wv = t >> 6;
  int wm = (wv & 1) * 64, wn = (wv >> 1) * 64;
  f32x4 acc[4][4];
#pragma unroll
  for (int i = 0; i < 4; ++i)
#pragma unroll
    for (int j = 0; j < 4; ++j) acc[i][j] = (f32x4){0.f, 0.f, 0.f, 0.f};
  const short* Ag = (const short*)A;
  const short* Bg = (const short*)BT;
  int sr = t >> 2;
  int sc = (t & 3) * 8;
  int rb0 = n0 + sr, rb1 = n0 + sr + 64;
  bool bv0 = rb0 < N, bv1 = rb1 < N;
  const short* Ap0 = Ag + (size_t)(m0 + sr) * K + sc;
  const short* Ap1 = Ag + (size_t)(m0 + sr + 64) * K + sc;
  const short* Bp0 = Bg + (size_t)rb0 * K + sc;
  const short* Bp1 = Bg + (size_t)rb1 * K + sc;
  int kTiles = (K + 31) >> 5;
  short8 a0 = 0, a1 = 0, b0 = 0, b1 = 0;
  auto loadt = [&](int k0) {
    a0 = *(const short8*)(Ap0 + k0);
    a1 = *(const short8*)(Ap1 + k0);
    b0 = bv0 ? *(const short8*)(Bp0 + k0) : (short8)0;
    b1 = bv1 ? *(const short8*)(Bp1 + k0) : (short8)0;
  };
  loadt(0);
  int fr = lane & 15, fq = (lane >> 4) * 8;
  for (int kt = 0; kt < kTiles; ++kt) {
    __syncthreads();
    *(short8*)&As[sr][sc] = a0;
    *(short8*)&As[sr + 64][sc] = a1;
    *(short8*)&Bs[sr][sc] = b0;
    *(short8*)&Bs[sr + 64][sc] = b1;
    __syncthreads();
    if (kt + 1 < kTiles) loadt((kt + 1) << 5);   // prefetch; overlaps MFMA
    short8 af[4], bfr[4];
#pragma unroll
    for (int i = 0; i < 4; ++i) af[i] = *(const short8*)&As[wm + i * 16 + fr][fq];
#pragma unroll
    for (int i = 0; i < 4; ++i) bfr[i] = *(const short8*)&Bs[wn + i * 16 + fr][fq];
#pragma unroll
    for (int mi = 0; mi < 4; ++mi)
#pragma unroll
      for (int ni = 0; ni < 4; ++ni)
        acc[mi][ni] = __builtin_amdgcn_mfma_f32_16x16x32_bf16(af[mi], bfr[ni], acc[mi][ni], 0, 0, 0);
  }
  int fq4 = (lane >> 4) * 4;
#pragma unroll
  for (int mi = 0; mi < 4; ++mi)
#pragma unroll
    for (int ni = 0; ni < 4; ++ni) {
      int col = n0 + wn + ni * 16 + fr;
      if (col < N) {
        int rowb = m0 + wm + mi * 16 + fq4;
#pragma unroll
        for (int r = 0; r < 4; ++r)
          C[(size_t)(rowb + r) * N + col] = f2bf(acc[mi][ni][r]);
      }
    }
}

// ---------------- GEMM 64x64, BK=64, register-pipelined, fused epilogue ----------------
// MODE 1: out = aux + acc*mask[row]; MODE 2: out = (aux + acc)*mask[row]. N exact (512).
// GATE=1: A-tile = silu(h1)*h3 computed from Hf (row stride FSTR) during staging; K padded, Kreal guards.
template <int MODE, int GATE>
__global__ __launch_bounds__(256) void gemm64_ep_kernel(
    const __hip_bfloat16* __restrict__ A, const __hip_bfloat16* __restrict__ BT,
    const float* __restrict__ aux, const float* __restrict__ mask,
    float* __restrict__ out, int M, int N, int K, int Kreal) {
  __shared__ short As[64][72];
  __shared__ short Bs[64][72];
  int m0 = blockIdx.x * 64, n0 = blockIdx.y * 64;
  int t = threadIdx.x;
  int lane = t & 63, wv = t >> 6;
  int wm = (wv & 1) * 32, wn = (wv >> 1) * 32;
  f32x4 acc[2][2];
#pragma unroll
  for (int i = 0; i < 2; ++i)
#pragma unroll
    for (int j = 0; j < 2; ++j) acc[i][j] = (f32x4){0.f, 0.f, 0.f, 0.f};
  const short* Ag = (const short*)A;
  const short* Bg = (const short*)BT;
  int sr = t >> 2;
  int sc = (t & 3) * 16;
  const short* Bp = Bg + (size_t)(n0 + sr) * K + sc;
  short8 a0 = 0, a1 = 0, b0 = 0, b1 = 0;
  auto loadt = [&](int k0) {
    b0 = *(const short8*)(Bp + k0);
    b1 = *(const short8*)(Bp + k0 + 8);
    if (GATE) {
      const short* hrow = Ag + (size_t)(m0 + sr) * FSTR;
      int k = k0 + sc;
      short8 h1a = *(const short8*)(hrow + k);
      short8 h1b = *(const short8*)(hrow + k + 8);
      short8 h3a = *(const short8*)(hrow + DFFn + k);
      short8 h3b = *(const short8*)(hrow + DFFn + k + 8);
#pragma unroll
      for (int j = 0; j < 8; ++j) {
        float v = bfs2f(h1a[j]);
        float sil = v / (1.f + __expf(-v));
        a0[j] = (k + j < Kreal) ? f2bfs(sil * bfs2f(h3a[j])) : (short)0;
        float v2 = bfs2f(h1b[j]);
        float sil2 = v2 / (1.f + __expf(-v2));
        a1[j] = (k + 8 + j < Kreal) ? f2bfs(sil2 * bfs2f(h3b[j])) : (short)0;
      }
    } else {
      const short* Ap = Ag + (size_t)(m0 + sr) * K + sc;
      a0 = *(const short8*)(Ap + k0);
      a1 = *(const short8*)(Ap + k0 + 8);
    }
  };
  loadt(0);
  int fr = lane & 15, fq = (lane >> 4) * 8;
  int kTiles = K >> 6;
  for (int kt = 0; kt < kTiles; ++kt) {
    __syncthreads();
    *(short8*)&As[sr][sc] = a0;
    *(short8*)&As[sr][sc + 8] = a1;
    *(short8*)&Bs[sr][sc] = b0;
    *(short8*)&Bs[sr][sc + 8] = b1;
    __syncthreads();
    if (kt + 1 < kTiles) loadt((kt + 1) << 6);
#pragma unroll
    for (int kk = 0; kk < 2; ++kk) {
      short8 af[2], bfr[2];
#pragma unroll
      for (int i = 0; i < 2; ++i) af[i] = *(const short8*)&As[wm + i * 16 + fr][kk * 32 + fq];
#pragma unroll
      for (int i = 0; i < 2; ++i) bfr[i] = *(const short8*)&Bs[wn + i * 16 + fr][kk * 32 + fq];
#pragma unroll
      for (int mi = 0; mi < 2; ++mi)
#pragma unroll
        for (int ni = 0; ni < 2; ++ni)
          acc[mi][ni] = __builtin_amdgcn_mfma_f32_16x16x32_bf16(af[mi], bfr[ni], acc[mi][ni], 0, 0, 0);
    }
  }
  int fq4 = (lane >> 4) * 4;
#pragma unroll
  for (int mi = 0; mi < 2; ++mi)
#pragma unroll
    for (int ni = 0; ni < 2; ++ni) {
      int col = n0 + wn + ni * 16 + fr;
#pragma unroll
      for (int r = 0; r < 4; ++r) {
        int row = m0 + wm + mi * 16 + fq4 + r;
        float m = mask[row];
        size_t a = (size_t)row * N + col;
        float v = acc[mi][ni][r];
        if (MODE == 1) out[a] = aux[a] + v * m;
        else           out[a] = (aux[a] + v) * m;
      }
    }
}

// ---------------- chunked scan: intra-chunk + chunk-state ----------------
__global__ __launch_bounds__(256) void chunk_intra_kernel(
    const __hip_bfloat16* __restrict__ P, const float* __restrict__ dt,
    const float* __restrict__ la, float* __restrict__ ys,
    float* __restrict__ Sbuf, float* __restrict__ ecL, float* __restrict__ ec) {
  int id = blockIdx.x;
  int h = id & 15, c = (id >> 4) & 7, b = id >> 7;
  int t = threadIdx.x, lane = t & 63, wv = t >> 6;
  __shared__ __align__(16) char smem[55040];
  short* sCB = (short*)smem;             // sC [64][136] (phase<=3a), sBt [128][72] (phase>=3b)
  short* sB  = (short*)(smem + 18432);   // [64][136]
  short* sUD = (short*)(smem + 35840);   // [64 p][72]  (s-minor)
  short* sG  = (short*)(smem + 45056);   // [64 t][72]  (s-minor)
  float* scum = (float*)(smem + 54272);  // [64]
  float* sws  = scum + 64;
  float* sdt  = sws + 64;
  int row0 = b * Sn + c * CH;
  const short* Pb = (const short*)P;
#pragma unroll
  for (int i = 0; i < 4; ++i) {
    int idx = t + i * 256;
    int r = idx >> 4, kk = (idx & 15) * 8;
    *(short8*)&sCB[r * 136 + kk] = *(const short8*)(Pb + (size_t)(row0 + r) * PSTR + 4096 + h * 128 + kk);
    *(short8*)&sB [r * 136 + kk] = *(const short8*)(Pb + (size_t)(row0 + r) * PSTR + 2048 + h * 128 + kk);
  }
  if (t < 64) { sdt[t] = dt[(size_t)(row0 + t) * Hn + h]; scum[t] = la[(size_t)(row0 + t) * Hn + h]; }
  __syncthreads();
  if (wv == 0) {
    float v = scum[lane];
#pragma unroll
    for (int o = 1; o < 64; o <<= 1) { float n = __shfl_up(v, o); if (lane >= o) v += n; }
    scum[lane] = v;
    float c63 = __shfl(v, 63);
    sws[lane] = __expf(c63 - v);
    ec[((size_t)((b * NCH + c) * Hn + h)) * 64 + lane] = __expf(v);
    if (lane == 0) ecL[(b * NCH + c) * Hn + h] = __expf(c63);
  }
#pragma unroll
  for (int i = 0; i < 2; ++i) {
    int idx = t + i * 256;
    int s = idx >> 3, pc = (idx & 7) * 8;
    short8 uv = *(const short8*)(Pb + (size_t)(row0 + s) * PSTR + 1024 + h * 64 + pc);
    float dv = sdt[s];
#pragma unroll
    for (int j = 0; j < 8; ++j) sUD[(pc + j) * 72 + s] = f2bfs(bfs2f(uv[j]) * dv);
  }
  __syncthreads();
  int fr = lane & 15, fq = (lane >> 4) * 8, q4 = (lane >> 4) * 4;
  {
    short8 af[4];
#pragma unroll
    for (int k = 0; k < 4; ++k) af[k] = *(short8*)&sCB[(16 * wv + fr) * 136 + k * 32 + fq];
#pragma unroll
    for (int j = 0; j < 4; ++j) {
      f32x4 acc = (f32x4){0.f, 0.f, 0.f, 0.f};
#pragma unroll
      for (int k = 0; k < 4; ++k) {
        short8 bf = *(short8*)&sB[(16 * j + fr) * 136 + k * 32 + fq];
        acc = __builtin_amdgcn_mfma_f32_16x16x32_bf16(af[k], bf, acc, 0, 0, 0);
      }
      int ss = 16 * j + fr;
      float cs = scum[ss];
#pragma unroll
      for (int r = 0; r < 4; ++r) {
        int tt = 16 * wv + q4 + r;
        float w = (ss <= tt) ? __expf(scum[tt] - cs) : 0.f;
        sG[tt * 72 + ss] = f2bfs(acc[r] * w);
      }
    }
  }
  __syncthreads();
#pragma unroll
  for (int i = 0; i < 32; ++i) {
    int idx = t + i * 256;
    int rn = idx >> 6, s = idx & 63;
    sCB[rn * 72 + s] = f2bfs(bfs2f(sB[s * 136 + rn]) * sws[s]);
  }
  __syncthreads();
  {
    short8 ag[2];
#pragma unroll
    for (int k = 0; k < 2; ++k) ag[k] = *(short8*)&sG[(16 * wv + fr) * 72 + k * 32 + fq];
#pragma unroll
    for (int j = 0; j < 4; ++j) {
      f32x4 acc = (f32x4){0.f, 0.f, 0.f, 0.f};
#pragma unroll
      for (int k = 0; k < 2; ++k) {
        short8 bf = *(short8*)&sUD[(16 * j + fr) * 72 + k * 32 + fq];
        acc = __builtin_amdgcn_mfma_f32_16x16x32_bf16(ag[k], bf, acc, 0, 0, 0);
      }
#pragma unroll
      for (int r = 0; r < 4; ++r)
        ys[(size_t)(row0 + 16 * wv + q4 + r) * DINn + h * 64 + 16 * j + fr] = acc[r];
    }
  }
#pragma unroll
  for (int mt0 = 0; mt0 < 2; ++mt0) {
    int mt = wv * 2 + mt0;
    short8 ab[2];
#pragma unroll
    for (int k = 0; k < 2; ++k) ab[k] = *(short8*)&sCB[(16 * mt + fr) * 72 + k * 32 + fq];
#pragma unroll
    for (int j = 0; j < 4; ++j) {
      f32x4 acc = (f32x4){0.f, 0.f, 0.f, 0.f};
#pragma unroll
      for (int k = 0; k < 2; ++k) {
        short8 bf = *(short8*)&sUD[(16 * j + fr) * 72 + k * 32 + fq];
        acc = __builtin_amdgcn_mfma_f32_16x16x32_bf16(ab[k], bf, acc, 0, 0, 0);
      }
#pragma unroll
      for (int r = 0; r < 4; ++r)
        Sbuf[((size_t)((b * NCH + c) * Hn + h) * RNn + 16 * mt + q4 + r) * 64 + 16 * j + fr] = acc[r];
    }
  }
}

// ---------------- inter-chunk + chunk-state prefix + gate, all fused:
// Hp = sum_{c'<c} w(c')*S[c'] (registers); y2 = (ys + ecum[t]*(C @ Hp) + u*D_skip)*silu(z) ----------------
__global__ __launch_bounds__(256) void inter_gate_kernel(
    const __hip_bfloat16* __restrict__ P, const float* __restrict__ Sbuf,
    const float* __restrict__ ecL, const float* __restrict__ ec,
    const float* __restrict__ ys, const float* __restrict__ Dsk,
    __hip_bfloat16* __restrict__ y2b) {
  int id = blockIdx.x;
  int h = id & 15, c = (id >> 4) & 7, b = id >> 7;
  int t = threadIdx.x, lane = t & 63, wv = t >> 6;
  __shared__ __align__(16) short sC[64 * 136];
  __shared__ __align__(16) short sHt[64 * 136];      // [p][rn]
  __shared__ __align__(16) short sz[64 * 64];
  __shared__ __align__(16) short su[64 * 64];
  __shared__ float sec[64];
  int row0 = b * Sn + c * CH;
  const short* Pb = (const short*)P;
#pragma unroll
  for (int i = 0; i < 2; ++i) {
    int idx = t + i * 256;
    int r = idx >> 3, pc = (idx & 7) * 8;
    *(short8*)&sz[r * 64 + pc] = *(const short8*)(Pb + (size_t)(row0 + r) * PSTR + h * 64 + pc);
    *(short8*)&su[r * 64 + pc] = *(const short8*)(Pb + (size_t)(row0 + r) * PSTR + 1024 + h * 64 + pc);
  }
  if (c > 0) {
#pragma unroll
    for (int i = 0; i < 4; ++i) {
      int idx = t + i * 256;
      int r = idx >> 4, kk = (idx & 15) * 8;
      *(short8*)&sC[r * 136 + kk] = *(const short8*)(Pb + (size_t)(row0 + r) * PSTR + 4096 + h * 128 + kk);
    }
    if (t < 64) sec[t] = ec[((size_t)((b * NCH + c) * Hn + h)) * 64 + t];
    // decay-weighted prefix of chunk states, accumulated in registers
    f32x4 hv[8];
#pragma unroll
    for (int i = 0; i < 8; ++i) hv[i] = (f32x4){0.f, 0.f, 0.f, 0.f};
    float wgt = 1.f;
#pragma unroll
    for (int d = 0; d < NCH - 1; ++d) {
      int cp = c - 1 - d;
      if (cp >= 0) {
        const float* Sb = Sbuf + ((size_t)((b * NCH + cp) * Hn + h)) * 8192;
#pragma unroll
        for (int i = 0; i < 8; ++i) {
          f32x4 sv = *(const f32x4*)(Sb + i * 1024 + t * 4);
#pragma unroll
          for (int j = 0; j < 4; ++j) hv[i][j] = fmaf(wgt, sv[j], hv[i][j]);
        }
        wgt *= ecL[(b * NCH + cp) * Hn + h];
      }
    }
    // scatter to bf16 [p][rn] for MFMA B-fragment
#pragma unroll
    for (int i = 0; i < 8; ++i)
#pragma unroll
      for (int j = 0; j < 4; ++j) {
        int e = i * 1024 + t * 4 + j;
        int rn = e >> 6, p = e & 63;
        sHt[p * 136 + rn] = f2bfs(hv[i][j]);
      }
  }
  __syncthreads();
  int fr = lane & 15, fq = (lane >> 4) * 8, q4 = (lane >> 4) * 4;
  f32x4 acc[4];
#pragma unroll
  for (int j = 0; j < 4; ++j) acc[j] = (f32x4){0.f, 0.f, 0.f, 0.f};
  if (c > 0) {
    short8 af[4];
#pragma unroll
    for (int k = 0; k < 4; ++k) af[k] = *(short8*)&sC[(16 * wv + fr) * 136 + k * 32 + fq];
#pragma unroll
    for (int j = 0; j < 4; ++j)
#pragma unroll
      for (int k = 0; k < 4; ++k) {
        short8 bf = *(short8*)&sHt[(16 * j + fr) * 136 + k * 32 + fq];
        acc[j] = __builtin_amdgcn_mfma_f32_16x16x32_bf16(af[k], bf, acc[j], 0, 0, 0);
      }
  }
  float dsk = Dsk[h];
#pragma unroll
  for (int j = 0; j < 4; ++j) {
    int col = 16 * j + fr;
#pragma unroll
    for (int r = 0; r < 4; ++r) {
      int tt = 16 * wv + q4 + r;
      size_t a = (size_t)(row0 + tt) * DINn + h * 64 + col;
      float val = ys[a];
      if (c > 0) val += sec[tt] * acc[j][r];
      float uu = bfs2f(su[tt * 64 + col]);
      float zz = bfs2f(sz[tt * 64 + col]);
      float sil = zz / (1.f + __expf(-zz));
      y2b[a] = f2bf((val + uu * dsk) * sil);
    }
  }
}

extern "C" void kernel_launch(void* const* d_in, const int* in_sizes, int n_in,
                              void* d_out, int out_size, void* d_ws, size_t ws_size,
                              hipStream_t stream) {
  const float* x    = (const float*)d_in[0];
  const float* mask = (const float*)d_in[1];
  const float* n1w  = (const float*)d_in[2];
  const float* n2w  = (const float*)d_in[3];
  const float* Wz   = (const float*)d_in[4];
  const float* Wx   = (const float*)d_in[5];
  const float* Wb   = (const float*)d_in[6];
  const float* Wc   = (const float*)d_in[7];
  const float* Wdt  = (const float*)d_in[8];
  const float* dtb  = (const float*)d_in[9];
  const float* Alog = (const float*)d_in[10];
  const float* Dsk  = (const float*)d_in[11];
  const float* Wout = (const float*)d_in[12];
  const float* w1   = (const float*)d_in[13];
  const float* w2   = (const float*)d_in[14];
  const float* w3   = (const float*)d_in[15];

  char* ws = (char*)d_ws;
  size_t off = 0;
  auto alloc = [&](size_t bytes) {
    char* p = ws + off;
    off += (bytes + 255) & ~(size_t)255;
    return p;
  };
  __hip_bfloat16* xnb = (__hip_bfloat16*)alloc((size_t)BSn * Dn * 2);
  __hip_bfloat16* P = (__hip_bfloat16*)alloc((size_t)BSn * PSTR * 2);
  float* dt  = (float*)alloc((size_t)BSn * Hn * 4);
  float* la  = (float*)alloc((size_t)BSn * Hn * 4);
  float* ys  = (float*)alloc((size_t)BSn * DINn * 4);
  float* ecL = (float*)alloc((size_t)Bn * NCH * Hn * 4);
  float* ec  = (float*)alloc((size_t)Bn * NCH * Hn * 64 * 4);
  __hip_bfloat16* WallT = (__hip_bfloat16*)alloc((size_t)PSTR * Dn * 2);   // [z|u|B|C]^T
  __hip_bfloat16* WoutT = (__hip_bfloat16*)alloc((size_t)Dn * DINn * 2);
  __hip_bfloat16* w13T  = (__hip_bfloat16*)alloc((size_t)FSTR * Dn * 2);   // [w1|w3]^T
  __hip_bfloat16* w2T   = (__hip_bfloat16*)alloc((size_t)Dn * 1408 * 2);   // K-pad 1408 (BK=64)
  // overlaid arena:
  //   Sbuf [0, 16.78M)            live: chunk_intra -> inter_gate
  //   y2b  [16.78M, 20.98M)       live: inter_gate -> gemm64<1>
  //   xres [8.39M, 12.58M)        live: gemm64<1> -> gemm64<2>   (over dead Sbuf)
  //   Hf   [12.58M, 23.79M)       live: ffn gemm -> gemm64<2>    (over dead Sbuf tail + y2b)
  char* arena = alloc(34000000);
  float* Sbuf = (float*)arena;
  __hip_bfloat16* y2b = (__hip_bfloat16*)(arena + 16777216);
  float* xres = (float*)(arena + 8388608);
  __hip_bfloat16* Hf = (__hip_bfloat16*)(arena + 12582912);

  // -------- transpose job table (single dispatch) --------
  T8 td;
  td.src[0] = Wz;   td.dst[0] = WallT;                      td.Rr[0] = 512;  td.Cc[0] = 1024; td.RrPad[0] = 512;  td.CcPad[0] = 1024;
  td.src[1] = Wx;   td.dst[1] = WallT + (size_t)1024 * 512; td.Rr[1] = 512;  td.Cc[1] = 1024; td.RrPad[1] = 512;  td.CcPad[1] = 1024;
  td.src[2] = Wb;   td.dst[2] = WallT + (size_t)2048 * 512; td.Rr[2] = 512;  td.Cc[2] = 2048; td.RrPad[2] = 512;  td.CcPad[2] = 2048;
  td.src[3] = Wc;   td.dst[3] = WallT + (size_t)4096 * 512; td.Rr[3] = 512;  td.Cc[3] = 2048; td.RrPad[3] = 512;  td.CcPad[3] = 2048;
  td.src[4] = Wout; td.dst[4] = WoutT;                      td.Rr[4] = 1024; td.Cc[4] = 512;  td.RrPad[4] = 1024; td.CcPad[4] = 512;
  td.src[5] = w1;   td.dst[5] = w13T;                       td.Rr[5] = 512;  td.Cc[5] = 1368; td.RrPad[5] = 512;  td.CcPad[5] = 1368;
  td.src[6] = w3;   td.dst[6] = w13T + (size_t)1368 * 512;  td.Rr[6] = 512;  td.Cc[6] = 1368; td.RrPad[6] = 512;  td.CcPad[6] = 1368;
  td.src[7] = w2;   td.dst[7] = w2T;                        td.Rr[7] = 1368; td.Cc[7] = 512;  td.RrPad[7] = 1408; td.CcPad[7] = 512;  // zero K-pad
  int tot = 0;
  for (int i = 0; i < 8; ++i) {
    td.gw[i] = (td.CcPad[i] + 31) / 32;
    int gh = (td.RrPad[i] + 31) / 32;
    td.start[i] = tot;
    tot += td.gw[i] * gh;
  }
  td.start[8] = tot;

  transpose8_kernel<<<tot, dim3(32, 8), 0, stream>>>(td);
  rmsnorm1_dt_kernel<<<BSn, 256, 0, stream>>>(x, n1w, mask, Wdt, dtb, Alog, xnb, dt, la);
  gemm_kernel<<<dim3(16, 48), 256, 0, stream>>>(xnb, WallT, P, BSn, PSTR, Dn);
  chunk_intra_kernel<<<Bn * NCH * Hn, 256, 0, stream>>>(P, dt, la, ys, Sbuf, ecL, ec);
  inter_gate_kernel<<<Bn * NCH * Hn, 256, 0, stream>>>(P, Sbuf, ecL, ec, ys, Dsk, y2b);
  gemm64_ep_kernel<1, 0><<<dim3(32, 8), 256, 0, stream>>>(y2b, WoutT, x, mask, xres, BSn, Dn, DINn, DINn);
  rmsnorm2_kernel<<<BSn, 256, 0, stream>>>(xres, n2w, xnb);
  gemm_kernel<<<dim3(16, 22), 256, 0, stream>>>(xnb, w13T, Hf, BSn, FSTR, Dn);
  gemm64_ep_kernel<2, 1><<<dim3(32, 8), 256, 0, stream>>>(Hf, w2T, xres, mask, (float*)d_out, BSn, Dn, 1408, DFFn);
}